// Round 8
// baseline (539.271 us; speedup 1.0000x reference)
//
#include <hip/hip_runtime.h>
#include <math.h>

#define NEG_SLOPE 0.2f

typedef __attribute__((ext_vector_type(8))) short bfrag8;
typedef __attribute__((ext_vector_type(4))) float f4acc;

__device__ __forceinline__ float bflo(unsigned int u) {
  union { unsigned int i; float f; } c;
  c.i = u << 16;
  return c.f;
}
__device__ __forceinline__ float bfhi(unsigned int u) {
  union { unsigned int i; float f; } c;
  c.i = u & 0xFFFF0000u;
  return c.f;
}
__device__ __forceinline__ unsigned short f2bf(float f) {
  union { float f; unsigned int i; } c;
  c.f = f;
  unsigned int i = c.i;
  return (unsigned short)((i + 0x7FFFu + ((i >> 16) & 1u)) >> 16);
}
// fast ELU: __expf(x)-1 instead of expm1f (libm). Error ~1e-7 abs near 0, < bf16 rounding.
__device__ __forceinline__ float elu(float x) { return x > 0.f ? x : __expf(x) - 1.f; }

// ---------------- CSR build: hist + last-block scan fused ----------------

__global__ __launch_bounds__(1024) void histscan_kernel(const int* __restrict__ ei,
                                                        int* __restrict__ counts,
                                                        int* __restrict__ done,
                                                        int* __restrict__ offsets,
                                                        int* __restrict__ cursor,
                                                        int n, int e) {
  int i = blockIdx.x * 1024 + threadIdx.x;
  if (i < e) atomicAdd(&counts[ei[e + i]], 1);
  __threadfence();  // release our atomics
  __syncthreads();
  __shared__ int lastFlag;
  if (threadIdx.x == 0) lastFlag = (atomicAdd(done, 1) == (int)gridDim.x - 1);
  __syncthreads();
  if (!lastFlag) return;
  __threadfence();  // acquire all blocks' atomics

  // tile-wise coalesced exclusive scan of counts[i]+1 -> offsets, cursor
  const volatile int* cv = counts;
  __shared__ int tileOff;
  __shared__ int wsum[16];
  int tid = threadIdx.x;
  if (tid == 0) tileOff = 0;
  __syncthreads();
  int nt = (n + 1023) >> 10;
  int lane = tid & 63, wv = tid >> 6;
  for (int tb = 0; tb < nt; ++tb) {
    int idx = tb * 1024 + tid;
    int v = (idx < n) ? cv[idx] + 1 : 0;
    int ws = v;
#pragma unroll
    for (int off = 1; off < 64; off <<= 1) {
      int t = __shfl_up(ws, off, 64);
      if (lane >= off) ws += t;
    }
    if (lane == 63) wsum[wv] = ws;
    __syncthreads();
    int woff = 0;
#pragma unroll
    for (int k = 0; k < 15; ++k)
      if (k < wv) woff += wsum[k];
    int incl = woff + ws;
    int excl = tileOff + incl - v;
    if (idx < n) {
      offsets[idx] = excl;
      cursor[idx] = excl;
    }
    __syncthreads();
    if (tid == 1023) tileOff += incl;  // incl of last thread = tile total
    __syncthreads();
  }
  if (tid == 0) offsets[n] = tileOff;
}

// fill: edges + self loops + zero the 64-entry csr pad
__global__ __launch_bounds__(256) void fill_kernel(const int* __restrict__ ei,
                                                   int* __restrict__ cursor,
                                                   int* __restrict__ csr, int n, int e) {
  int i = blockIdx.x * 256 + threadIdx.x;
  if (i < e) {
    int s = ei[i];
    int d = ei[e + i];
    int pos = atomicAdd(&cursor[d], 1);
    csr[pos] = s;
  } else if (i < e + n) {
    int node = i - e;
    int pos = atomicAdd(&cursor[node], 1);
    csr[pos] = node;
  } else if (i < e + n + 64) {
    csr[i] = 0;  // pad
  }
}

// ---------------- cast: xb = bf16(x); w1t[c][k], w2t[c][k] transposed bf16 ----------------

__global__ __launch_bounds__(256) void cast_kernel(const float* __restrict__ x,
                                                   const float* __restrict__ W1,
                                                   const float* __restrict__ W2,
                                                   unsigned short* __restrict__ xb,
                                                   unsigned short* __restrict__ w1t,
                                                   unsigned short* __restrict__ w2t,
                                                   int xThreads, int totalx) {
  int gid = blockIdx.x * 256 + threadIdx.x;
  if (gid < xThreads) {
    int i = gid * 8;
    if (i >= totalx) return;
    float4 v0 = *(const float4*)(x + i);
    float4 v1 = *(const float4*)(x + i + 4);
    uint4 q;
    q.x = (unsigned int)f2bf(v0.x) | ((unsigned int)f2bf(v0.y) << 16);
    q.y = (unsigned int)f2bf(v0.z) | ((unsigned int)f2bf(v0.w) << 16);
    q.z = (unsigned int)f2bf(v1.x) | ((unsigned int)f2bf(v1.y) << 16);
    q.w = (unsigned int)f2bf(v1.z) | ((unsigned int)f2bf(v1.w) << 16);
    *(uint4*)(xb + i) = q;
    return;
  }
  int g2 = gid - xThreads;
#pragma unroll
  for (int u = 0; u < 4; ++u) {
    int j = g2 * 4 + u;
    if (j < 128 * 256) {
      int k = j >> 8, c = j & 255;
      w1t[c * 128 + k] = f2bf(W1[j]);
    } else if (j < 128 * 256 + 256 * 32) {
      int j2 = j - 128 * 256;
      int k = j2 >> 5, c = j2 & 31;
      w2t[c * 256 + k] = f2bf(W2[j2]);
    }
  }
}

// ---------------- GEMM1 (MFMA bf16, +fused att1) ----------------

__global__ __launch_bounds__(256) void gemm1_kernel(const unsigned short* __restrict__ xb,
                                                    const unsigned short* __restrict__ w1t,
                                                    const float* __restrict__ att_src,
                                                    const float* __restrict__ att_dst,
                                                    unsigned short* __restrict__ h1b,
                                                    float* __restrict__ as1,
                                                    float* __restrict__ ad1, int n) {
  int tid = threadIdx.x;
  int wave = tid >> 6, lane = tid & 63;
  int quad = lane >> 4, l16 = lane & 15;
  int row0 = blockIdx.x * 64 + wave * 16;
  int col0 = blockIdx.y * 128;
  int rowA = min(row0 + l16, n - 1);

  f4acc acc[8];
#pragma unroll
  for (int t = 0; t < 8; ++t) acc[t] = (f4acc)(0.f);

#pragma unroll
  for (int kc = 0; kc < 4; ++kc) {
    bfrag8 a = *(const bfrag8*)(xb + (size_t)rowA * 128 + kc * 32 + quad * 8);
#pragma unroll
    for (int t = 0; t < 8; ++t) {
      bfrag8 b = *(const bfrag8*)(w1t + (size_t)(col0 + t * 16 + l16) * 128 + kc * 32 + quad * 8);
      acc[t] = __builtin_amdgcn_mfma_f32_16x16x32_bf16(a, b, acc[t], 0, 0, 0);
    }
  }

#pragma unroll
  for (int r = 0; r < 4; ++r) {
    int gr = row0 + quad * 4 + r;
    if (gr < n) {
#pragma unroll
      for (int t = 0; t < 8; ++t)
        h1b[(size_t)gr * 256 + col0 + t * 16 + l16] = f2bf(acc[t][r]);
    }
  }

  float s1[4][4], s2[4][4];
#pragma unroll
  for (int r = 0; r < 4; ++r)
#pragma unroll
    for (int hl = 0; hl < 4; ++hl) { s1[r][hl] = 0.f; s2[r][hl] = 0.f; }
#pragma unroll
  for (int t = 0; t < 8; ++t) {
    float av = att_src[col0 + t * 16 + l16];
    float dv = att_dst[col0 + t * 16 + l16];
    int hl = t >> 1;
#pragma unroll
    for (int r = 0; r < 4; ++r) {
      s1[r][hl] += acc[t][r] * av;
      s2[r][hl] += acc[t][r] * dv;
    }
  }
#pragma unroll
  for (int r = 0; r < 4; ++r) {
#pragma unroll
    for (int hl = 0; hl < 4; ++hl) {
      float v1 = s1[r][hl], v2 = s2[r][hl];
      v1 += __shfl_xor(v1, 1); v1 += __shfl_xor(v1, 2);
      v1 += __shfl_xor(v1, 4); v1 += __shfl_xor(v1, 8);
      v2 += __shfl_xor(v2, 1); v2 += __shfl_xor(v2, 2);
      v2 += __shfl_xor(v2, 4); v2 += __shfl_xor(v2, 8);
      if (l16 == 0) {
        int gr = row0 + quad * 4 + r;
        if (gr < n) {
          int hg = (col0 >> 5) + hl;
          as1[(size_t)gr * 8 + hg] = v1;
          ad1[(size_t)gr * 8 + hg] = v2;
        }
      }
    }
  }
}

// ---------------- layer-1 aggregation ----------------

__global__ __launch_bounds__(256) void agg1_kernel(const unsigned short* __restrict__ h1b,
                                                   const float* __restrict__ as1,
                                                   const float* __restrict__ ad1,
                                                   const int* __restrict__ offsets,
                                                   const int* __restrict__ csr,
                                                   const float* __restrict__ bias,
                                                   unsigned short* __restrict__ h1ob, int n) {
  __shared__ float peLds[4 * 64 * 8];
  int gtid = blockIdx.x * 256 + threadIdx.x;
  int node = gtid >> 6;
  int lane = gtid & 63;
  if (node >= n) return;
  float* myPe = peLds + (threadIdx.x >> 6) * 512;
  int beg = offsets[node], end = offsets[node + 1];
  int deg = end - beg;
  int half = lane >> 5, sub = lane & 31, head = sub >> 2;

  float4 adv0 = ((const float4*)(ad1 + (size_t)node * 8))[0];
  float4 adv1 = ((const float4*)(ad1 + (size_t)node * 8))[1];
  float ad_[8] = {adv0.x, adv0.y, adv0.z, adv0.w, adv1.x, adv1.y, adv1.z, adv1.w};

  float l = 0.f;
  float a[8] = {};

  for (int c0 = 0; c0 < deg; c0 += 64) {
    int cnt = min(64, deg - c0);
    bool valid = (c0 + lane) < deg;
    int s = csr[beg + c0 + lane];
    {
      const float4* ap = (const float4*)(as1 + (size_t)s * 8);
      float4 r0 = ap[0], r1 = ap[1];
      float asv[8] = {r0.x, r0.y, r0.z, r0.w, r1.x, r1.y, r1.z, r1.w};
      float pv[8];
#pragma unroll
      for (int h = 0; h < 8; ++h) {
        float ev = asv[h] + ad_[h];
        ev = ev > 0.f ? ev : NEG_SLOPE * ev;
        pv[h] = valid ? __expf(ev) : 0.f;
      }
      *(float4*)&myPe[lane * 8 + 0] = make_float4(pv[0], pv[1], pv[2], pv[3]);
      *(float4*)&myPe[lane * 8 + 4] = make_float4(pv[4], pv[5], pv[6], pv[7]);
    }
#pragma unroll 4
    for (int j = 0; j < cnt; j += 2) {
      int e = j + half;
      int s2 = csr[beg + c0 + e];
      float pe = myPe[e * 8 + head];
      l += pe;
      uint4 hv = *(const uint4*)(h1b + (size_t)s2 * 256 + sub * 8);
      a[0] += pe * bflo(hv.x);
      a[1] += pe * bfhi(hv.x);
      a[2] += pe * bflo(hv.y);
      a[3] += pe * bfhi(hv.y);
      a[4] += pe * bflo(hv.z);
      a[5] += pe * bfhi(hv.z);
      a[6] += pe * bflo(hv.w);
      a[7] += pe * bfhi(hv.w);
    }
  }
  l += __shfl_xor(l, 32);
#pragma unroll
  for (int i = 0; i < 8; ++i) a[i] += __shfl_xor(a[i], 32);

  if (half == 0) {
    float inv = 1.f / (l + 1e-16f);
    const float4* bp = (const float4*)(bias + sub * 8);
    float4 b0 = bp[0], b1 = bp[1];
    float o[8];
    o[0] = elu(a[0] * inv + b0.x);
    o[1] = elu(a[1] * inv + b0.y);
    o[2] = elu(a[2] * inv + b0.z);
    o[3] = elu(a[3] * inv + b0.w);
    o[4] = elu(a[4] * inv + b1.x);
    o[5] = elu(a[5] * inv + b1.y);
    o[6] = elu(a[6] * inv + b1.z);
    o[7] = elu(a[7] * inv + b1.w);
    unsigned int q[4];
#pragma unroll
    for (int j = 0; j < 4; ++j)
      q[j] = (unsigned int)f2bf(o[j * 2]) | ((unsigned int)f2bf(o[j * 2 + 1]) << 16);
    *(uint4*)(h1ob + (size_t)node * 256 + sub * 8) = make_uint4(q[0], q[1], q[2], q[3]);
  }
}

// ---------------- GEMM2 (MFMA bf16, +fused att2) ----------------

__global__ __launch_bounds__(256) void gemm2_kernel(const unsigned short* __restrict__ h1ob,
                                                    const unsigned short* __restrict__ w2t,
                                                    const float* __restrict__ att_src,
                                                    const float* __restrict__ att_dst,
                                                    unsigned short* __restrict__ h2b,
                                                    float* __restrict__ as2,
                                                    float* __restrict__ ad2, int n) {
  int tid = threadIdx.x;
  int wave = tid >> 6, lane = tid & 63;
  int quad = lane >> 4, l16 = lane & 15;
  int row0 = blockIdx.x * 64 + wave * 16;
  int rowA = min(row0 + l16, n - 1);

  f4acc acc[2];
  acc[0] = (f4acc)(0.f);
  acc[1] = (f4acc)(0.f);

#pragma unroll
  for (int kc = 0; kc < 8; ++kc) {
    bfrag8 a = *(const bfrag8*)(h1ob + (size_t)rowA * 256 + kc * 32 + quad * 8);
#pragma unroll
    for (int t = 0; t < 2; ++t) {
      bfrag8 b = *(const bfrag8*)(w2t + (size_t)(t * 16 + l16) * 256 + kc * 32 + quad * 8);
      acc[t] = __builtin_amdgcn_mfma_f32_16x16x32_bf16(a, b, acc[t], 0, 0, 0);
    }
  }

#pragma unroll
  for (int r = 0; r < 4; ++r) {
    int gr = row0 + quad * 4 + r;
    if (gr < n) {
      h2b[(size_t)gr * 32 + l16] = f2bf(acc[0][r]);
      h2b[(size_t)gr * 32 + 16 + l16] = f2bf(acc[1][r]);
    }
  }

  float s1[4], s2v[4];
#pragma unroll
  for (int r = 0; r < 4; ++r) { s1[r] = 0.f; s2v[r] = 0.f; }
#pragma unroll
  for (int t = 0; t < 2; ++t) {
    float av = att_src[t * 16 + l16];
    float dv = att_dst[t * 16 + l16];
#pragma unroll
    for (int r = 0; r < 4; ++r) {
      s1[r] += acc[t][r] * av;
      s2v[r] += acc[t][r] * dv;
    }
  }
#pragma unroll
  for (int r = 0; r < 4; ++r) {
    float v1 = s1[r], v2 = s2v[r];
    v1 += __shfl_xor(v1, 1); v1 += __shfl_xor(v1, 2);
    v1 += __shfl_xor(v1, 4); v1 += __shfl_xor(v1, 8);
    v2 += __shfl_xor(v2, 1); v2 += __shfl_xor(v2, 2);
    v2 += __shfl_xor(v2, 4); v2 += __shfl_xor(v2, 8);
    if (l16 == 0) {
      int gr = row0 + quad * 4 + r;
      if (gr < n) {
        as2[gr] = v1;
        ad2[gr] = v2;
      }
    }
  }
}

// ---------------- layer-2 aggregation (+fused output proj) ----------------

__global__ __launch_bounds__(256) void agg2_kernel(const unsigned short* __restrict__ h2b,
                                                   const float* __restrict__ as2,
                                                   const float* __restrict__ ad2,
                                                   const int* __restrict__ offsets,
                                                   const int* __restrict__ csr,
                                                   const float* __restrict__ bias,
                                                   const float* __restrict__ Wout,
                                                   const float* __restrict__ bout,
                                                   float* __restrict__ out, int n) {
  __shared__ float peLds[4 * 64];
  __shared__ float wLds[512];
  __shared__ float hrow[4][32];
  int tid = threadIdx.x;
  wLds[tid] = Wout[tid];
  wLds[tid + 256] = Wout[tid + 256];
  __syncthreads();

  int gtid = blockIdx.x * 256 + tid;
  int node = gtid >> 6;
  int lane = gtid & 63;
  if (node >= n) return;
  int wv = tid >> 6;
  float* myPe = peLds + wv * 64;
  float ad = ad2[node];
  int beg = offsets[node], end = offsets[node + 1];
  int deg = end - beg;
  int quarter = lane >> 4;
  int dsub = lane & 15;

  float l = 0.f, a0 = 0.f, a1 = 0.f;
  for (int c0 = 0; c0 < deg; c0 += 64) {
    int cnt = min(64, deg - c0);
    bool valid = (c0 + lane) < deg;
    int s = csr[beg + c0 + lane];
    float ev = as2[s] + ad;
    ev = ev > 0.f ? ev : NEG_SLOPE * ev;
    myPe[lane] = valid ? __expf(ev) : 0.f;
#pragma unroll 4
    for (int j = 0; j < cnt; j += 4) {
      int e = j + quarter;
      int s2 = csr[beg + c0 + e];
      float pe = myPe[e];
      l += pe;
      unsigned int hv = *(const unsigned int*)(h2b + (size_t)s2 * 32 + dsub * 2);
      a0 += pe * bflo(hv);
      a1 += pe * bfhi(hv);
    }
  }
  l += __shfl_xor(l, 16);
  l += __shfl_xor(l, 32);
  a0 += __shfl_xor(a0, 16);
  a1 += __shfl_xor(a1, 16);
  a0 += __shfl_xor(a0, 32);
  a1 += __shfl_xor(a1, 32);
  if (lane < 16) {
    float inv = 1.f / (l + 1e-16f);
    float o0 = elu(a0 * inv + bias[dsub * 2]);
    float o1 = elu(a1 * inv + bias[dsub * 2 + 1]);
    hrow[wv][dsub * 2] = o0;
    hrow[wv][dsub * 2 + 1] = o1;
  }
  if (lane < 16) {
    float s = bout[lane];
#pragma unroll
    for (int c = 0; c < 32; ++c) s += hrow[wv][c] * wLds[c * 16 + lane];
    out[(size_t)node * 16 + lane] = s;
  }
}

// ---------------- launch ----------------

extern "C" void kernel_launch(void* const* d_in, const int* in_sizes, int n_in,
                              void* d_out, int out_size, void* d_ws, size_t ws_size,
                              hipStream_t stream) {
  const float* x        = (const float*)d_in[0];
  const int*   ei       = (const int*)d_in[1];
  const float* W1       = (const float*)d_in[2];
  const float* att_src1 = (const float*)d_in[3];
  const float* att_dst1 = (const float*)d_in[4];
  const float* b1       = (const float*)d_in[5];
  const float* W2       = (const float*)d_in[6];
  const float* att_src2 = (const float*)d_in[7];
  const float* att_dst2 = (const float*)d_in[8];
  const float* b2       = (const float*)d_in[9];
  const float* Wout     = (const float*)d_in[10];
  const float* bout     = (const float*)d_in[11];
  float* out = (float*)d_out;

  int n = in_sizes[0] / 128;  // 50000
  int e = in_sizes[1] / 2;    // 800000

  char* w = (char*)d_ws;
  unsigned short* h1b  = (unsigned short*)w; w += (size_t)n * 256 * 2;
  unsigned short* h1ob = (unsigned short*)w; w += (size_t)n * 256 * 2;
  unsigned short* xb   = (unsigned short*)w; w += (size_t)n * 128 * 2;
  unsigned short* h2b  = (unsigned short*)w; w += (size_t)n * 32 * 2;
  unsigned short* w1t  = (unsigned short*)w; w += (size_t)256 * 128 * 2;
  unsigned short* w2t  = (unsigned short*)w; w += (size_t)32 * 256 * 2;
  float* as1  = (float*)w; w += (size_t)n * 8 * 4;
  float* ad1  = (float*)w; w += (size_t)n * 8 * 4;
  float* as2  = (float*)w; w += (size_t)n * 4;
  float* ad2  = (float*)w; w += (size_t)n * 4;
  int* counts  = (int*)w; w += (size_t)n * 4;
  int* done    = (int*)w; w += (size_t)16 * 4;   // adjacent to counts; zeroed together
  int* offsets = (int*)w; w += (size_t)(n + 16) * 4;
  int* cursor  = (int*)w; w += (size_t)n * 4;
  int* csr     = (int*)w; w += (size_t)(e + n + 64) * 4;

  // CSR by dst: memset -> hist+scan (last-block) -> fill
  hipMemsetAsync(counts, 0, (size_t)(n + 16) * 4, stream);
  int nbh = (e + 1023) / 1024;
  histscan_kernel<<<nbh, 1024, 0, stream>>>(ei, counts, done, offsets, cursor, n, e);
  fill_kernel<<<(e + n + 64 + 255) / 256, 256, 0, stream>>>(ei, cursor, csr, n, e);

  // casts (x -> bf16, W1/W2 -> transposed bf16) in one kernel
  int xThreads = (n * 128 + 7) / 8;  // 800000
  int castThreads = xThreads + (128 * 256 + 256 * 32 + 3) / 4;
  cast_kernel<<<(castThreads + 255) / 256, 256, 0, stream>>>(x, W1, W2, xb, w1t, w2t,
                                                             xThreads, n * 128);

  // layer 1
  gemm1_kernel<<<dim3((n + 63) / 64, 2), 256, 0, stream>>>(xb, w1t, att_src1, att_dst1,
                                                           h1b, as1, ad1, n);
  agg1_kernel<<<(n + 3) / 4, 256, 0, stream>>>(h1b, as1, ad1, offsets, csr, b1, h1ob, n);

  // layer 2
  gemm2_kernel<<<(n + 63) / 64, 256, 0, stream>>>(h1ob, w2t, att_src2, att_dst2,
                                                  h2b, as2, ad2, n);
  agg2_kernel<<<(n + 3) / 4, 256, 0, stream>>>(h2b, as2, ad2, offsets, csr, b2,
                                               Wout, bout, out, n);
}

// Round 9
// 334.486 us; speedup vs baseline: 1.6122x; 1.6122x over previous
//
#include <hip/hip_runtime.h>
#include <math.h>

#define NEG_SLOPE 0.2f

typedef __attribute__((ext_vector_type(8))) short bfrag8;
typedef __attribute__((ext_vector_type(4))) float f4acc;

__device__ __forceinline__ float bflo(unsigned int u) {
  union { unsigned int i; float f; } c;
  c.i = u << 16;
  return c.f;
}
__device__ __forceinline__ float bfhi(unsigned int u) {
  union { unsigned int i; float f; } c;
  c.i = u & 0xFFFF0000u;
  return c.f;
}
__device__ __forceinline__ unsigned short f2bf(float f) {
  union { float f; unsigned int i; } c;
  c.f = f;
  unsigned int i = c.i;
  return (unsigned short)((i + 0x7FFFu + ((i >> 16) & 1u)) >> 16);
}
// fast ELU: __expf(x)-1 instead of expm1f (libm call). err ~1e-7, < bf16 rounding.
__device__ __forceinline__ float elu(float x) { return x > 0.f ? x : __expf(x) - 1.f; }

// ---------------- prep: histogram + x/W casts (independent work, one dispatch) ----------------

__global__ __launch_bounds__(256) void prep_kernel(const int* __restrict__ ei,
                                                   int* __restrict__ counts,
                                                   const float* __restrict__ x,
                                                   const float* __restrict__ W1,
                                                   const float* __restrict__ W2,
                                                   unsigned short* __restrict__ xb,
                                                   unsigned short* __restrict__ w1t,
                                                   unsigned short* __restrict__ w2t,
                                                   int e, int xThreads, int totalx) {
  int gid = blockIdx.x * 256 + threadIdx.x;
  if (gid < e) {
    atomicAdd(&counts[ei[e + gid]], 1);
    return;
  }
  int g1 = gid - e;
  if (g1 < xThreads) {
    int i = g1 * 8;
    if (i < totalx) {
      float4 v0 = *(const float4*)(x + i);
      float4 v1 = *(const float4*)(x + i + 4);
      uint4 q;
      q.x = (unsigned int)f2bf(v0.x) | ((unsigned int)f2bf(v0.y) << 16);
      q.y = (unsigned int)f2bf(v0.z) | ((unsigned int)f2bf(v0.w) << 16);
      q.z = (unsigned int)f2bf(v1.x) | ((unsigned int)f2bf(v1.y) << 16);
      q.w = (unsigned int)f2bf(v1.z) | ((unsigned int)f2bf(v1.w) << 16);
      *(uint4*)(xb + i) = q;
    }
    return;
  }
  int g2 = g1 - xThreads;
#pragma unroll
  for (int u = 0; u < 4; ++u) {
    int j = g2 * 4 + u;
    if (j < 128 * 256) {
      int k = j >> 8, c = j & 255;
      w1t[c * 128 + k] = f2bf(W1[j]);
    } else if (j < 128 * 256 + 256 * 32) {
      int j2 = j - 128 * 256;
      int k = j2 >> 5, c = j2 & 31;
      w2t[c * 256 + k] = f2bf(W2[j2]);
    }
  }
}

// ---------------- scan (R7 structure: multi-block + tiny fixup) ----------------

#define SCAN_TILE 2048
__global__ __launch_bounds__(256) void scan1_kernel(const int* __restrict__ counts,
                                                    int* __restrict__ offsets,
                                                    int* __restrict__ bsum, int n) {
  __shared__ int wtot[4];
  int tid = threadIdx.x;
  int base = blockIdx.x * SCAN_TILE + tid * 8;
  int v[8];
#pragma unroll
  for (int k = 0; k < 8; ++k) v[k] = (base + k < n) ? counts[base + k] + 1 : 0;
#pragma unroll
  for (int k = 1; k < 8; ++k) v[k] += v[k - 1];
  int tsum = v[7];
  int lane = tid & 63;
  int w = tid >> 6;
  int ws = tsum;
#pragma unroll
  for (int off = 1; off < 64; off <<= 1) {
    int t = __shfl_up(ws, off, 64);
    if (lane >= off) ws += t;
  }
  if (lane == 63) wtot[w] = ws;
  __syncthreads();
  int woff = 0;
#pragma unroll
  for (int k = 0; k < 3; ++k)
    if (k < w) woff += wtot[k];
  int thrBase = woff + ws - tsum;
#pragma unroll
  for (int k = 0; k < 8; ++k)
    if (base + k < n) offsets[base + k] = thrBase + v[k];  // block-inclusive
  if (tid == 255) bsum[blockIdx.x] = woff + ws;            // block total
}

__global__ __launch_bounds__(256) void scan3_kernel(const int* __restrict__ counts,
                                                    int* __restrict__ offsets,
                                                    const int* __restrict__ bsum,
                                                    int* __restrict__ cursor,
                                                    int n, int nb) {
  __shared__ int pres[64];
  int tid = threadIdx.x;
  if (tid < 64) {
    int v = (tid < nb) ? bsum[tid] : 0;
#pragma unroll
    for (int off = 1; off < 64; off <<= 1) {
      int t = __shfl_up(v, off, 64);
      if ((tid & 63) >= off) v += t;
    }
    pres[tid] = v;
  }
  __syncthreads();
  int i = blockIdx.x * 256 + tid;
  if (i > n) return;
  if (i == n) {
    offsets[n] = pres[nb - 1];
    return;
  }
  int b = i >> 11;
  int pre = (b == 0) ? 0 : pres[b - 1];
  int excl = pre + offsets[i] - (counts[i] + 1);
  offsets[i] = excl;
  cursor[i] = excl;
}

__global__ __launch_bounds__(256) void fill_kernel(const int* __restrict__ ei,
                                                   int* __restrict__ cursor,
                                                   int* __restrict__ csr, int n, int e) {
  int i = blockIdx.x * 256 + threadIdx.x;
  if (i < e) {
    int s = ei[i];
    int d = ei[e + i];
    int pos = atomicAdd(&cursor[d], 1);
    csr[pos] = s;
  } else if (i < e + n) {
    int node = i - e;
    int pos = atomicAdd(&cursor[node], 1);
    csr[pos] = node;
  } else if (i < e + n + 64) {
    csr[i] = 0;  // pad
  }
}

// ---------------- GEMM1 (MFMA bf16, +fused att1) ----------------

__global__ __launch_bounds__(256) void gemm1_kernel(const unsigned short* __restrict__ xb,
                                                    const unsigned short* __restrict__ w1t,
                                                    const float* __restrict__ att_src,
                                                    const float* __restrict__ att_dst,
                                                    unsigned short* __restrict__ h1b,
                                                    float* __restrict__ as1,
                                                    float* __restrict__ ad1, int n) {
  int tid = threadIdx.x;
  int wave = tid >> 6, lane = tid & 63;
  int quad = lane >> 4, l16 = lane & 15;
  int row0 = blockIdx.x * 64 + wave * 16;
  int col0 = blockIdx.y * 128;
  int rowA = min(row0 + l16, n - 1);

  f4acc acc[8];
#pragma unroll
  for (int t = 0; t < 8; ++t) acc[t] = (f4acc)(0.f);

#pragma unroll
  for (int kc = 0; kc < 4; ++kc) {
    bfrag8 a = *(const bfrag8*)(xb + (size_t)rowA * 128 + kc * 32 + quad * 8);
#pragma unroll
    for (int t = 0; t < 8; ++t) {
      bfrag8 b = *(const bfrag8*)(w1t + (size_t)(col0 + t * 16 + l16) * 128 + kc * 32 + quad * 8);
      acc[t] = __builtin_amdgcn_mfma_f32_16x16x32_bf16(a, b, acc[t], 0, 0, 0);
    }
  }

#pragma unroll
  for (int r = 0; r < 4; ++r) {
    int gr = row0 + quad * 4 + r;
    if (gr < n) {
#pragma unroll
      for (int t = 0; t < 8; ++t)
        h1b[(size_t)gr * 256 + col0 + t * 16 + l16] = f2bf(acc[t][r]);
    }
  }

  float s1[4][4], s2[4][4];
#pragma unroll
  for (int r = 0; r < 4; ++r)
#pragma unroll
    for (int hl = 0; hl < 4; ++hl) { s1[r][hl] = 0.f; s2[r][hl] = 0.f; }
#pragma unroll
  for (int t = 0; t < 8; ++t) {
    float av = att_src[col0 + t * 16 + l16];
    float dv = att_dst[col0 + t * 16 + l16];
    int hl = t >> 1;
#pragma unroll
    for (int r = 0; r < 4; ++r) {
      s1[r][hl] += acc[t][r] * av;
      s2[r][hl] += acc[t][r] * dv;
    }
  }
#pragma unroll
  for (int r = 0; r < 4; ++r) {
#pragma unroll
    for (int hl = 0; hl < 4; ++hl) {
      float v1 = s1[r][hl], v2 = s2[r][hl];
      v1 += __shfl_xor(v1, 1); v1 += __shfl_xor(v1, 2);
      v1 += __shfl_xor(v1, 4); v1 += __shfl_xor(v1, 8);
      v2 += __shfl_xor(v2, 1); v2 += __shfl_xor(v2, 2);
      v2 += __shfl_xor(v2, 4); v2 += __shfl_xor(v2, 8);
      if (l16 == 0) {
        int gr = row0 + quad * 4 + r;
        if (gr < n) {
          int hg = (col0 >> 5) + hl;
          as1[(size_t)gr * 8 + hg] = v1;
          ad1[(size_t)gr * 8 + hg] = v2;
        }
      }
    }
  }
}

// ---------------- layer-1 aggregation ----------------

__global__ __launch_bounds__(256) void agg1_kernel(const unsigned short* __restrict__ h1b,
                                                   const float* __restrict__ as1,
                                                   const float* __restrict__ ad1,
                                                   const int* __restrict__ offsets,
                                                   const int* __restrict__ csr,
                                                   const float* __restrict__ bias,
                                                   unsigned short* __restrict__ h1ob, int n) {
  __shared__ float peLds[4 * 64 * 8];
  int gtid = blockIdx.x * 256 + threadIdx.x;
  int node = gtid >> 6;
  int lane = gtid & 63;
  if (node >= n) return;
  float* myPe = peLds + (threadIdx.x >> 6) * 512;
  int beg = offsets[node], end = offsets[node + 1];
  int deg = end - beg;
  int half = lane >> 5, sub = lane & 31, head = sub >> 2;

  float4 adv0 = ((const float4*)(ad1 + (size_t)node * 8))[0];
  float4 adv1 = ((const float4*)(ad1 + (size_t)node * 8))[1];
  float ad_[8] = {adv0.x, adv0.y, adv0.z, adv0.w, adv1.x, adv1.y, adv1.z, adv1.w};

  float l = 0.f;
  float a[8] = {};

  for (int c0 = 0; c0 < deg; c0 += 64) {
    int cnt = min(64, deg - c0);
    bool valid = (c0 + lane) < deg;
    int s = csr[beg + c0 + lane];
    {
      const float4* ap = (const float4*)(as1 + (size_t)s * 8);
      float4 r0 = ap[0], r1 = ap[1];
      float asv[8] = {r0.x, r0.y, r0.z, r0.w, r1.x, r1.y, r1.z, r1.w};
      float pv[8];
#pragma unroll
      for (int h = 0; h < 8; ++h) {
        float ev = asv[h] + ad_[h];
        ev = ev > 0.f ? ev : NEG_SLOPE * ev;
        pv[h] = valid ? __expf(ev) : 0.f;
      }
      *(float4*)&myPe[lane * 8 + 0] = make_float4(pv[0], pv[1], pv[2], pv[3]);
      *(float4*)&myPe[lane * 8 + 4] = make_float4(pv[4], pv[5], pv[6], pv[7]);
    }
#pragma unroll 4
    for (int j = 0; j < cnt; j += 2) {
      int e = j + half;
      int s2 = csr[beg + c0 + e];
      float pe = myPe[e * 8 + head];
      l += pe;
      uint4 hv = *(const uint4*)(h1b + (size_t)s2 * 256 + sub * 8);
      a[0] += pe * bflo(hv.x);
      a[1] += pe * bfhi(hv.x);
      a[2] += pe * bflo(hv.y);
      a[3] += pe * bfhi(hv.y);
      a[4] += pe * bflo(hv.z);
      a[5] += pe * bfhi(hv.z);
      a[6] += pe * bflo(hv.w);
      a[7] += pe * bfhi(hv.w);
    }
  }
  l += __shfl_xor(l, 32);
#pragma unroll
  for (int i = 0; i < 8; ++i) a[i] += __shfl_xor(a[i], 32);

  if (half == 0) {
    float inv = 1.f / (l + 1e-16f);
    const float4* bp = (const float4*)(bias + sub * 8);
    float4 b0 = bp[0], b1 = bp[1];
    float o[8];
    o[0] = elu(a[0] * inv + b0.x);
    o[1] = elu(a[1] * inv + b0.y);
    o[2] = elu(a[2] * inv + b0.z);
    o[3] = elu(a[3] * inv + b0.w);
    o[4] = elu(a[4] * inv + b1.x);
    o[5] = elu(a[5] * inv + b1.y);
    o[6] = elu(a[6] * inv + b1.z);
    o[7] = elu(a[7] * inv + b1.w);
    unsigned int q[4];
#pragma unroll
    for (int j = 0; j < 4; ++j)
      q[j] = (unsigned int)f2bf(o[j * 2]) | ((unsigned int)f2bf(o[j * 2 + 1]) << 16);
    *(uint4*)(h1ob + (size_t)node * 256 + sub * 8) = make_uint4(q[0], q[1], q[2], q[3]);
  }
}

// ---------------- GEMM2 (MFMA bf16, +fused att2) ----------------

__global__ __launch_bounds__(256) void gemm2_kernel(const unsigned short* __restrict__ h1ob,
                                                    const unsigned short* __restrict__ w2t,
                                                    const float* __restrict__ att_src,
                                                    const float* __restrict__ att_dst,
                                                    unsigned short* __restrict__ h2b,
                                                    float* __restrict__ as2,
                                                    float* __restrict__ ad2, int n) {
  int tid = threadIdx.x;
  int wave = tid >> 6, lane = tid & 63;
  int quad = lane >> 4, l16 = lane & 15;
  int row0 = blockIdx.x * 64 + wave * 16;
  int rowA = min(row0 + l16, n - 1);

  f4acc acc[2];
  acc[0] = (f4acc)(0.f);
  acc[1] = (f4acc)(0.f);

#pragma unroll
  for (int kc = 0; kc < 8; ++kc) {
    bfrag8 a = *(const bfrag8*)(h1ob + (size_t)rowA * 256 + kc * 32 + quad * 8);
#pragma unroll
    for (int t = 0; t < 2; ++t) {
      bfrag8 b = *(const bfrag8*)(w2t + (size_t)(t * 16 + l16) * 256 + kc * 32 + quad * 8);
      acc[t] = __builtin_amdgcn_mfma_f32_16x16x32_bf16(a, b, acc[t], 0, 0, 0);
    }
  }

#pragma unroll
  for (int r = 0; r < 4; ++r) {
    int gr = row0 + quad * 4 + r;
    if (gr < n) {
      h2b[(size_t)gr * 32 + l16] = f2bf(acc[0][r]);
      h2b[(size_t)gr * 32 + 16 + l16] = f2bf(acc[1][r]);
    }
  }

  float s1[4], s2v[4];
#pragma unroll
  for (int r = 0; r < 4; ++r) { s1[r] = 0.f; s2v[r] = 0.f; }
#pragma unroll
  for (int t = 0; t < 2; ++t) {
    float av = att_src[t * 16 + l16];
    float dv = att_dst[t * 16 + l16];
#pragma unroll
    for (int r = 0; r < 4; ++r) {
      s1[r] += acc[t][r] * av;
      s2v[r] += acc[t][r] * dv;
    }
  }
#pragma unroll
  for (int r = 0; r < 4; ++r) {
    float v1 = s1[r], v2 = s2v[r];
    v1 += __shfl_xor(v1, 1); v1 += __shfl_xor(v1, 2);
    v1 += __shfl_xor(v1, 4); v1 += __shfl_xor(v1, 8);
    v2 += __shfl_xor(v2, 1); v2 += __shfl_xor(v2, 2);
    v2 += __shfl_xor(v2, 4); v2 += __shfl_xor(v2, 8);
    if (l16 == 0) {
      int gr = row0 + quad * 4 + r;
      if (gr < n) {
        as2[gr] = v1;
        ad2[gr] = v2;
      }
    }
  }
}

// ---------------- layer-2 aggregation (+fused output proj) ----------------

__global__ __launch_bounds__(256) void agg2_kernel(const unsigned short* __restrict__ h2b,
                                                   const float* __restrict__ as2,
                                                   const float* __restrict__ ad2,
                                                   const int* __restrict__ offsets,
                                                   const int* __restrict__ csr,
                                                   const float* __restrict__ bias,
                                                   const float* __restrict__ Wout,
                                                   const float* __restrict__ bout,
                                                   float* __restrict__ out, int n) {
  __shared__ float peLds[4 * 64];
  __shared__ float wLds[512];
  __shared__ float hrow[4][32];
  int tid = threadIdx.x;
  wLds[tid] = Wout[tid];
  wLds[tid + 256] = Wout[tid + 256];
  __syncthreads();

  int gtid = blockIdx.x * 256 + tid;
  int node = gtid >> 6;
  int lane = gtid & 63;
  if (node >= n) return;
  int wv = tid >> 6;
  float* myPe = peLds + wv * 64;
  float ad = ad2[node];
  int beg = offsets[node], end = offsets[node + 1];
  int deg = end - beg;
  int quarter = lane >> 4;
  int dsub = lane & 15;

  float l = 0.f, a0 = 0.f, a1 = 0.f;
  for (int c0 = 0; c0 < deg; c0 += 64) {
    int cnt = min(64, deg - c0);
    bool valid = (c0 + lane) < deg;
    int s = csr[beg + c0 + lane];
    float ev = as2[s] + ad;
    ev = ev > 0.f ? ev : NEG_SLOPE * ev;
    myPe[lane] = valid ? __expf(ev) : 0.f;
#pragma unroll 4
    for (int j = 0; j < cnt; j += 4) {
      int e = j + quarter;
      int s2 = csr[beg + c0 + e];
      float pe = myPe[e];
      l += pe;
      unsigned int hv = *(const unsigned int*)(h2b + (size_t)s2 * 32 + dsub * 2);
      a0 += pe * bflo(hv);
      a1 += pe * bfhi(hv);
    }
  }
  l += __shfl_xor(l, 16);
  l += __shfl_xor(l, 32);
  a0 += __shfl_xor(a0, 16);
  a1 += __shfl_xor(a1, 16);
  a0 += __shfl_xor(a0, 32);
  a1 += __shfl_xor(a1, 32);
  if (lane < 16) {
    float inv = 1.f / (l + 1e-16f);
    float o0 = elu(a0 * inv + bias[dsub * 2]);
    float o1 = elu(a1 * inv + bias[dsub * 2 + 1]);
    hrow[wv][dsub * 2] = o0;
    hrow[wv][dsub * 2 + 1] = o1;
  }
  if (lane < 16) {
    float s = bout[lane];
#pragma unroll
    for (int c = 0; c < 32; ++c) s += hrow[wv][c] * wLds[c * 16 + lane];
    out[(size_t)node * 16 + lane] = s;
  }
}

// ---------------- launch ----------------

extern "C" void kernel_launch(void* const* d_in, const int* in_sizes, int n_in,
                              void* d_out, int out_size, void* d_ws, size_t ws_size,
                              hipStream_t stream) {
  const float* x        = (const float*)d_in[0];
  const int*   ei       = (const int*)d_in[1];
  const float* W1       = (const float*)d_in[2];
  const float* att_src1 = (const float*)d_in[3];
  const float* att_dst1 = (const float*)d_in[4];
  const float* b1       = (const float*)d_in[5];
  const float* W2       = (const float*)d_in[6];
  const float* att_src2 = (const float*)d_in[7];
  const float* att_dst2 = (const float*)d_in[8];
  const float* b2       = (const float*)d_in[9];
  const float* Wout     = (const float*)d_in[10];
  const float* bout     = (const float*)d_in[11];
  float* out = (float*)d_out;

  int n = in_sizes[0] / 128;  // 50000
  int e = in_sizes[1] / 2;    // 800000

  char* w = (char*)d_ws;
  unsigned short* h1b  = (unsigned short*)w; w += (size_t)n * 256 * 2;
  unsigned short* h1ob = (unsigned short*)w; w += (size_t)n * 256 * 2;
  unsigned short* xb   = (unsigned short*)w; w += (size_t)n * 128 * 2;
  unsigned short* h2b  = (unsigned short*)w; w += (size_t)n * 32 * 2;
  unsigned short* w1t  = (unsigned short*)w; w += (size_t)256 * 128 * 2;
  unsigned short* w2t  = (unsigned short*)w; w += (size_t)32 * 256 * 2;
  float* as1  = (float*)w; w += (size_t)n * 8 * 4;
  float* ad1  = (float*)w; w += (size_t)n * 8 * 4;
  float* as2  = (float*)w; w += (size_t)n * 4;
  float* ad2  = (float*)w; w += (size_t)n * 4;
  int* counts  = (int*)w; w += (size_t)n * 4;
  int* offsets = (int*)w; w += (size_t)(n + 16) * 4;
  int* cursor  = (int*)w; w += (size_t)n * 4;
  int* csr     = (int*)w; w += (size_t)(e + n + 64) * 4;
  int* bsum    = (int*)w; w += (size_t)256 * 4;

  int nb = (n + SCAN_TILE - 1) / SCAN_TILE;  // 25

  // prep: zero counts, then hist + casts in one dispatch
  hipMemsetAsync(counts, 0, (size_t)n * 4, stream);
  int xThreads = (n * 128 + 7) / 8;  // 800000
  int prepThreads = e + xThreads + (128 * 256 + 256 * 32 + 3) / 4;
  prep_kernel<<<(prepThreads + 255) / 256, 256, 0, stream>>>(ei, counts, x, W1, W2,
                                                             xb, w1t, w2t, e, xThreads,
                                                             n * 128);

  // scan + fill
  scan1_kernel<<<nb, 256, 0, stream>>>(counts, offsets, bsum, n);
  scan3_kernel<<<(n + 256) / 256, 256, 0, stream>>>(counts, offsets, bsum, cursor, n, nb);
  fill_kernel<<<(e + n + 64 + 255) / 256, 256, 0, stream>>>(ei, cursor, csr, n, e);

  // layer 1
  gemm1_kernel<<<dim3((n + 63) / 64, 2), 256, 0, stream>>>(xb, w1t, att_src1, att_dst1,
                                                           h1b, as1, ad1, n);
  agg1_kernel<<<(n + 3) / 4, 256, 0, stream>>>(h1b, as1, ad1, offsets, csr, b1, h1ob, n);

  // layer 2
  gemm2_kernel<<<(n + 63) / 64, 256, 0, stream>>>(h1ob, w2t, att_src2, att_dst2,
                                                  h2b, as2, ad2, n);
  agg2_kernel<<<(n + 3) / 4, 256, 0, stream>>>(h2b, as2, ad2, offsets, csr, b2,
                                               Wout, bout, out, n);
}